// Round 8
// baseline (42.508 us; speedup 1.0000x reference)
//
#include <hip/hip_runtime.h>
#include <float.h>

#define BATCH 4

typedef _Float16 half8 __attribute__((ext_vector_type(8)));
typedef float f32x16 __attribute__((ext_vector_type(16)));
typedef float f32x2 __attribute__((ext_vector_type(2)));

// ================= MFMA path =================
// D[i,j] = |p_i|^2 + |q_j|^2 - 2 p.q  via K=13 fp16 slots (exact split):
//  A[p] = [hx,hy,hz, hx,hy,hz, ex,ey,ez, ps_h, ps_e, 1, 1, 0,0,0]
//  B[q] = [-2hx,-2hy,-2hz, -2ex,-2ey,-2ez, -2hx,-2hy,-2hz, 1, 1, qs_h, qs_e, 0,0,0]
// fp16*fp16 products are exact in the fp32 accumulator; only the dropped
// e.e term (~1e-6) and fp16(e) residual remain.  (Verified R7: absmax 4e-3.)

__device__ inline void pack_point(float x, float y, float z,
                                  _Float16* __restrict__ A, _Float16* __restrict__ B) {
    const _Float16 hx = (_Float16)x, hy = (_Float16)y, hz = (_Float16)z;
    const _Float16 ex = (_Float16)(x - (float)hx);
    const _Float16 ey = (_Float16)(y - (float)hy);
    const _Float16 ez = (_Float16)(z - (float)hz);
    const float ps = fmaf(x, x, fmaf(y, y, z * z));
    const _Float16 ph = (_Float16)ps;
    const _Float16 pe = (_Float16)(ps - (float)ph);
    const _Float16 one = (_Float16)1.0f, zero = (_Float16)0.0f;

    A[0]=hx; A[1]=hy; A[2]=hz; A[3]=hx; A[4]=hy; A[5]=hz;
    A[6]=ex; A[7]=ey; A[8]=ez; A[9]=ph; A[10]=pe; A[11]=one; A[12]=one;
    A[13]=zero; A[14]=zero; A[15]=zero;

    B[0]=(_Float16)(-2.0f*(float)hx); B[1]=(_Float16)(-2.0f*(float)hy); B[2]=(_Float16)(-2.0f*(float)hz);
    B[3]=(_Float16)(-2.0f*(float)ex); B[4]=(_Float16)(-2.0f*(float)ey); B[5]=(_Float16)(-2.0f*(float)ez);
    B[6]=B[0]; B[7]=B[1]; B[8]=B[2];
    B[9]=one; B[10]=one; B[11]=ph; B[12]=pe;
    B[13]=zero; B[14]=zero; B[15]=zero;
}

__global__ void prep_fp16(const float* __restrict__ x1, const float* __restrict__ x2,
                          _Float16* __restrict__ pa1, _Float16* __restrict__ pb1,
                          _Float16* __restrict__ pa2, _Float16* __restrict__ pb2,
                          float* __restrict__ out, int n1, int n2, int outn) {
    const int i = blockIdx.x * blockDim.x + threadIdx.x;
    if (i < n1) {
        const float* p = x1 + 3 * (size_t)i;
        pack_point(p[0], p[1], p[2], pa1 + 16 * (size_t)i, pb1 + 16 * (size_t)i);
    }
    if (i < n2) {
        const float* p = x2 + 3 * (size_t)i;
        pack_point(p[0], p[1], p[2], pa2 + 16 * (size_t)i, pb2 + 16 * (size_t)i);
    }
    if (i < outn) out[i] = FLT_MAX;
}

// Min-reduce v over the 32 lanes of each 32-lane half, pure-VALU DPP:
// 4x row_ror (within rows of 16) + row_bcast15 (row_mask 0xA: only rows 1,3
// updated, so the cross-32-lane bcast of lane31->row2 is masked off).
// Result lands in lanes 16..31 and 48..63.
__device__ inline float colmin32_dpp(float v) {
    int x = __builtin_bit_cast(int, v);
    x = __builtin_amdgcn_update_dpp(x, x, 0x121, 0xF, 0xF, false);  // row_ror:1
    v = fminf(v, __builtin_bit_cast(float, x));
    x = __builtin_bit_cast(int, v);
    x = __builtin_amdgcn_update_dpp(x, x, 0x122, 0xF, 0xF, false);  // row_ror:2
    v = fminf(v, __builtin_bit_cast(float, x));
    x = __builtin_bit_cast(int, v);
    x = __builtin_amdgcn_update_dpp(x, x, 0x124, 0xF, 0xF, false);  // row_ror:4
    v = fminf(v, __builtin_bit_cast(float, x));
    x = __builtin_bit_cast(int, v);
    x = __builtin_amdgcn_update_dpp(x, x, 0x128, 0xF, 0xF, false);  // row_ror:8
    v = fminf(v, __builtin_bit_cast(float, x));
    x = __builtin_bit_cast(int, v);
    x = __builtin_amdgcn_update_dpp(x, x, 0x142, 0xA, 0xF, false);  // row_bcast:15, rows 1&3 only
    v = fminf(v, __builtin_bit_cast(float, x));
    return v;
}

// Block: 4 waves x IT=2 i-tiles of 32 rows = 256 rows/block. Sweeps a
// j-segment (N/NJ cols) in LDS stages of 256 cols = 8 j-tiles of 32.
// B-frags stored fragment-linear: tile t, lane l at sB[t*64 + l] (16B each)
// -> ds_read_b128 at lane-consecutive addresses (canonical conflict-free).
// A frag (32x32x16_f16): row = lane&31, k = 8*(lane>>5)+j (8 contiguous f16).
// D: col = lane&31, row = (e&3) + 8*(e>>2) + 4*(lane>>5).
template<int NJ>
__global__ __launch_bounds__(256) void chamfer_mfma32(
        const _Float16* __restrict__ pa1, const _Float16* __restrict__ pb1,
        const _Float16* __restrict__ pa2, const _Float16* __restrict__ pb2,
        float* __restrict__ out, int N) {
    constexpr int IT = 2;
    __shared__ uint4 sB[512];   // 8 j-tiles * 64 frags * 16B = 8 KiB

    const int tid  = threadIdx.x;
    const int lane = tid & 63;
    const int w    = tid >> 6;

    int bid = blockIdx.x;
    const int RB      = N / 256;
    const int per_dir = BATCH * RB * NJ;
    const int dir = bid / per_dir;   bid %= per_dir;
    const int b   = bid / (RB * NJ); bid %= (RB * NJ);
    const int rb  = bid / NJ;
    const int js  = bid % NJ;

    const _Float16* pa = dir ? pa2 : pa1;
    const _Float16* pb = dir ? pb1 : pb2;
    float* outd = out + (size_t)dir * BATCH * N + (size_t)b * N;

    // A fragments from global: 16B per lane.
    const int rowbase = rb * 256 + w * 64;
    const uint4* ga = (const uint4*)pa;
    half8 af[IT];
    #pragma unroll
    for (int it = 0; it < IT; ++it) {
        const int row = rowbase + it * 32 + (lane & 31);
        af[it] = __builtin_bit_cast(half8, ga[(size_t)(b * N + row) * 2 + (lane >> 5)]);
    }

    f32x16 rmin[IT];
    #pragma unroll
    for (int it = 0; it < IT; ++it)
        #pragma unroll
        for (int e = 0; e < 16; ++e)
            rmin[it][e] = FLT_MAX;
    f32x16 cz;
    #pragma unroll
    for (int e = 0; e < 16; ++e) cz[e] = 0.0f;

    const int jseg   = N / NJ;
    const int stages = jseg / 256;
    const uint4* gb  = (const uint4*)pb;

    for (int s = 0; s < stages; ++s) {
        const int jb = js * jseg + s * 256;
        // ---- stage 256 packed cols (32B each) into LDS ----
        const size_t q = (size_t)(b * N + jb + tid) * 2;
        const uint4 v0 = gb[q];
        const uint4 v1 = gb[q + 1];
        const int t = tid >> 5, col = tid & 31;
        __syncthreads();                 // prior stage fully consumed
        sB[t * 64 + col]      = v0;      // k 0..7  -> lanes 0..31
        sB[t * 64 + 32 + col] = v1;      // k 8..15 -> lanes 32..63
        __syncthreads();

        // ---- 8 j-tiles as 4 pairs; min3 folds two tiles per accumulate ----
        #pragma unroll
        for (int p = 0; p < 4; ++p) {
            const half8 b0 = __builtin_bit_cast(half8, sB[(2 * p)     * 64 + lane]);
            const half8 b1 = __builtin_bit_cast(half8, sB[(2 * p + 1) * 64 + lane]);
            #pragma unroll
            for (int it = 0; it < IT; ++it) {
                const f32x16 d0 = __builtin_amdgcn_mfma_f32_32x32x16_f16(af[it], b0, cz, 0, 0, 0);
                const f32x16 d1 = __builtin_amdgcn_mfma_f32_32x32x16_f16(af[it], b1, cz, 0, 0, 0);
                #pragma unroll
                for (int e = 0; e < 16; ++e)
                    rmin[it][e] = fminf(fminf(rmin[it][e], d0[e]), d1[e]);  // v_min3_f32
            }
        }
    }

    // ---- DPP col-reduce (pure VALU), then 16 atomics from lanes 16/48 ----
    #pragma unroll
    for (int it = 0; it < IT; ++it) {
        #pragma unroll
        for (int e = 0; e < 16; ++e)
            rmin[it][e] = colmin32_dpp(rmin[it][e]);
        if ((lane & 31) == 16) {
            const int r0 = rowbase + it * 32 + 4 * (lane >> 5);
            #pragma unroll
            for (int e = 0; e < 16; ++e) {
                const float v = fmaxf(rmin[it][e], 0.0f);   // >=0 keeps int-min order
                atomicMin((int*)&outd[r0 + (e & 3) + 8 * (e >> 2)], __float_as_int(v));
            }
        }
    }
}

// ================= fallback: R6 pk-fma path =================
__global__ void chamfer_prep(const float* __restrict__ xyz1,
                             const float* __restrict__ xyz2,
                             float4* __restrict__ pk1,
                             float4* __restrict__ pk2,
                             float* __restrict__ out,
                             int n1, int n2, int out_n) {
    int i = blockIdx.x * blockDim.x + threadIdx.x;
    if (i < n1) {
        float x = xyz1[3 * (size_t)i], y = xyz1[3 * (size_t)i + 1], z = xyz1[3 * (size_t)i + 2];
        pk1[i] = make_float4(-2.f * x, -2.f * y, -2.f * z, fmaf(x, x, fmaf(y, y, z * z)));
    }
    if (i < n2) {
        float x = xyz2[3 * (size_t)i], y = xyz2[3 * (size_t)i + 1], z = xyz2[3 * (size_t)i + 2];
        pk2[i] = make_float4(-2.f * x, -2.f * y, -2.f * z, fmaf(x, x, fmaf(y, y, z * z)));
    }
    if (i < out_n) out[i] = FLT_MAX;
}

template<int TPB, int CHUNK, int P>
__global__ __launch_bounds__(TPB) void chamfer_fused(
        const float* __restrict__ xyz1, const float* __restrict__ xyz2,
        const float4* __restrict__ pk1, const float4* __restrict__ pk2,
        float* __restrict__ out, int N, int M, int blocks_dir0) {
    __shared__ float4 s[CHUNK];
    int bid = blockIdx.x;
    const int dir = (bid >= blocks_dir0) ? 1 : 0;
    if (dir) bid -= blocks_dir0;
    const int Nsrc = dir ? M : N;
    const int Mdst = dir ? N : M;
    const float* src   = dir ? xyz2 : xyz1;
    const float4* dstp = dir ? pk1  : pk2;
    float* outd        = dir ? (out + (size_t)BATCH * N) : out;
    const int YT = Nsrc / (TPB * P);
    const int Z  = Mdst / CHUNK;
    const int b  = bid / (YT * Z);
    const int r  = bid % (YT * Z);
    const int yt = r / Z;
    const int z  = r % Z;
    const float4* dchunk = dstp + (size_t)b * Mdst + (size_t)z * CHUNK;
    for (int t = threadIdx.x; t < CHUNK / 2; t += TPB) {
        const float4 q0 = dchunk[2 * t];
        const float4 q1 = dchunk[2 * t + 1];
        s[2 * t]     = make_float4(q0.x, q1.x, q0.y, q1.y);
        s[2 * t + 1] = make_float4(q0.z, q1.z, q0.w, q1.w);
    }
    const int i0 = yt * (TPB * P) + threadIdx.x;
    f32x2 px[P], py[P], pz[P];
    float psq[P], m[P];
    #pragma unroll
    for (int k = 0; k < P; ++k) {
        const int i = i0 + k * TPB;
        const float* p = src + ((size_t)b * Nsrc + i) * 3;
        const float x = p[0], y = p[1], zc = p[2];
        px[k] = (f32x2){x, x}; py[k] = (f32x2){y, y}; pz[k] = (f32x2){zc, zc};
        psq[k] = fmaf(x, x, fmaf(y, y, zc * zc));
        m[k] = FLT_MAX;
    }
    __syncthreads();
    #pragma unroll 8
    for (int jj = 0; jj < CHUNK / 2; ++jj) {
        const float4 A = s[2 * jj];
        const float4 B = s[2 * jj + 1];
        const f32x2 xq = (f32x2){A.x, A.y};
        const f32x2 yq = (f32x2){A.z, A.w};
        const f32x2 zq = (f32x2){B.x, B.y};
        const f32x2 wq = (f32x2){B.z, B.w};
        #pragma unroll
        for (int k = 0; k < P; ++k) {
            const f32x2 e = __builtin_elementwise_fma(xq, px[k],
                             __builtin_elementwise_fma(yq, py[k],
                              __builtin_elementwise_fma(zq, pz[k], wq)));
            m[k] = fminf(fminf(m[k], e.x), e.y);
        }
    }
    #pragma unroll
    for (int k = 0; k < P; ++k) {
        const int i = i0 + k * TPB;
        const float d = fmaxf(psq[k] + m[k], 0.0f);
        atomicMin((int*)&outd[(size_t)b * Nsrc + i], __float_as_int(d));
    }
}

extern "C" void kernel_launch(void* const* d_in, const int* in_sizes, int n_in,
                              void* d_out, int out_size, void* d_ws, size_t ws_size,
                              hipStream_t stream) {
    const float* xyz1 = (const float*)d_in[0];
    const float* xyz2 = (const float*)d_in[1];
    float* out = (float*)d_out;

    const int N = in_sizes[0] / (BATCH * 3);  // 8192
    const int M = in_sizes[1] / (BATCH * 3);  // 8192
    const int n1 = BATCH * N, n2 = BATCH * M;

    constexpr int TPB = 256;
    constexpr int NJ = 8;

    const size_t need16 = ((size_t)n1 + (size_t)n2) * 64;  // A+B fp16 forms
    const bool mfma_ok = (N == M) && (N % (NJ * 256) == 0) && (ws_size >= need16);

    if (mfma_ok) {
        _Float16* pa1 = (_Float16*)d_ws;
        _Float16* pb1 = pa1 + (size_t)n1 * 16;
        _Float16* pa2 = pb1 + (size_t)n1 * 16;
        _Float16* pb2 = pa2 + (size_t)n2 * 16;
        int prep_n = out_size > n1 ? out_size : n1;
        if (n2 > prep_n) prep_n = n2;
        prep_fp16<<<(prep_n + TPB - 1) / TPB, TPB, 0, stream>>>(
            xyz1, xyz2, pa1, pb1, pa2, pb2, out, n1, n2, out_size);

        const int grid = 2 * BATCH * (N / 256) * NJ;   // 2048
        chamfer_mfma32<NJ><<<grid, TPB, 0, stream>>>(pa1, pb1, pa2, pb2, out, N);
        return;
    }

    // fallback: R6 pk-fma path
    constexpr int CHUNK = 128;
    constexpr int P = 8;
    const size_t need = ((size_t)n1 + (size_t)n2) * sizeof(float4);
    if (ws_size >= need && (N % (TPB * P) == 0) && (M % (TPB * P) == 0) &&
        (N % CHUNK == 0) && (M % CHUNK == 0)) {
        float4* pk1 = (float4*)d_ws;
        float4* pk2 = pk1 + n1;
        int prep_n = out_size > n1 ? out_size : n1;
        if (n2 > prep_n) prep_n = n2;
        chamfer_prep<<<(prep_n + TPB - 1) / TPB, TPB, 0, stream>>>(
            xyz1, xyz2, pk1, pk2, out, n1, n2, out_size);
        const int blocks_dir0 = BATCH * (N / (TPB * P)) * (M / CHUNK);
        const int blocks_dir1 = BATCH * (M / (TPB * P)) * (N / CHUNK);
        chamfer_fused<TPB, CHUNK, P><<<blocks_dir0 + blocks_dir1, TPB, 0, stream>>>(
            xyz1, xyz2, pk1, pk2, out, N, M, blocks_dir0);
    }
}